// Round 16
// baseline (21.224 us; speedup 1.0000x reference)
//
#include <hip/hip_runtime.h>

// B=8192, F=256(K), N=128 trees, D=6, U=16, C=64
// cols = n*6+d  (768 total)
//
// Round 16: fix 4-way LDS bank conflicts on the gates slice.
//   gates row stride 48 u16 (96 B, banks 24r mod 32 -> 4-way) -> 52 u16
//   (104 B, banks 26r mod 32 -> conflict-free; 13 coprime 16).
//   EPI writes now hit disjoint bank quartets per lq group.
// Slices grow to 3328 B x 16 waves = 53.2 KB -> gates alias the xf region
// (xf moved to tail [49152,65536), dead after GEMM + barrier).
// GEMM reverts to kt-outer (xf reads 48 -> 16 per wave).

typedef float f32x4 __attribute__((ext_vector_type(4)));
typedef unsigned int u32;
typedef _Float16 h16;
typedef _Float16 h16x2 __attribute__((ext_vector_type(2)));
typedef _Float16 h16x8 __attribute__((ext_vector_type(8)));

typedef unsigned short __attribute__((may_alias)) u16a;
typedef u32            __attribute__((may_alias)) u32a;
typedef float          __attribute__((may_alias)) f32a;

#define MEMFENCE asm volatile("" ::: "memory")

// gates slice geometry (per wave)
#define GSTRIDE_U16 52          // row stride in u16 (104 B)
#define GSLICE_B    3328        // 32 rows * 104 B

// ws layout (bytes):
//   WpF   fp16 [48ct][8kt][64lane][8]  @ 0        393216 B
//   respF fp16 [128n][2kt][64lane][8]  @ 393216   262144 B
//   bias  f32  [768]                   @ 655360     3072 B
#define WPF_OFF   0
#define RESPF_OFF 393216
#define BIAS_OFF  655360

union h2u { h16x2 h; u32 u; };
union hbits { h16 h; unsigned short s; };
union fragh { u32 w[4]; h16x8 v; int4 i4; h16x2 h2[4]; };

__device__ inline unsigned short h16r(float f) {
    hbits t; t.h = (h16)f; return t.s;
}
__device__ inline u32 packh2(float a, float b) {
    h2u t; t.h[0] = (h16)a; t.h[1] = (h16)b; return t.u;
}

__device__ inline f32x4 mfma_f16(h16x8 a, h16x8 b, f32x4 c) {
    return __builtin_amdgcn_mfma_f32_16x16x32_f16(a, b, c, 0, 0, 0);
}

// ------------------------------------------------ prep kernel (round 15)
__global__ __launch_bounds__(1024) void k_prep(const float* __restrict__ fsl,
                                               const float* __restrict__ thr,
                                               const float* __restrict__ logt,
                                               const float* __restrict__ resp,
                                               unsigned short* __restrict__ WpF,
                                               unsigned short* __restrict__ respF,
                                               float* __restrict__ bias) {
    int bb  = blockIdx.x;
    int tid = threadIdx.x;
    if (bb < 32) {
        __shared__ unsigned short sm[32][192];
        int ib = (bb & 7) * 32;     // feature base; kt = bb&7 uniform per block
        int nb = (bb >> 3) * 32;    // tree base
        int il = tid >> 5;          // 0..31 local feature
        int nl = tid & 31;          // 0..31 local tree
        int i = ib + il;
        int n = nb + nl;
        const float* zp = fsl + (size_t)(i * 128 + n) * 6;

        float2 za = *(const float2*)(zp);
        float2 zb = *(const float2*)(zp + 2);
        float2 zc = *(const float2*)(zp + 4);
        float z[6] = {za.x, za.y, zb.x, zb.y, zc.x, zc.y};
        float zs[6];
        #pragma unroll
        for (int d = 0; d < 6; ++d) zs[d] = z[d];
        #pragma unroll
        for (int a = 0; a < 5; ++a) {
            #pragma unroll
            for (int b = a + 1; b < 6; ++b) {
                float hi = fmaxf(zs[a], zs[b]);
                float lo = fminf(zs[a], zs[b]);
                zs[a] = hi; zs[b] = lo;
            }
        }
        float cs = 0.f, csel = 0.f;
        int   km = 1;
        #pragma unroll
        for (int k = 0; k < 6; ++k) {
            cs += zs[k];
            if (1.0f + (float)(k + 1) * zs[k] > cs) { km = k + 1; csel = cs; }
        }
        float tau = (csel - 1.0f) / (float)km;

        const float* lp = logt + n * 6;
        float2 la = *(const float2*)(lp);
        float2 lb = *(const float2*)(lp + 2);
        float2 lc = *(const float2*)(lp + 4);
        float lt[6] = {la.x, la.y, lb.x, lb.y, lc.x, lc.y};

        #pragma unroll
        for (int d = 0; d < 6; ++d) {
            float invT = expf(-lt[d]);
            float sel  = fmaxf(z[d] - tau, 0.0f);
            sm[il][nl * 6 + d] = h16r(sel * 0.5f * invT);
            if (i == 0) bias[n * 6 + d] = 0.5f - 0.5f * invT * thr[n * 6 + d];
        }
        __syncthreads();

        if (tid < 768) {
            int lq  = tid / 192;
            int rem = tid - lq * 192;
            int ct  = (nb * 6) >> 4;
            ct += rem >> 4;
            int clm = rem & 15;
            int kt  = bb & 7;
            union { unsigned short s[8]; int4 i4; } o;
            #pragma unroll
            for (int j = 0; j < 8; ++j) o.s[j] = sm[lq * 8 + j][rem];
            *(int4*)(WpF + (size_t)(((ct * 8 + kt) * 64 + lq * 16 + clm) * 8)) = o.i4;
        }
    } else {
        int t = (bb - 32) * 1024 + tid;
        int n  = t >> 7;
        int k2 = (t >> 6) & 1;
        int l  = t & 63;
        int u  = l & 15;
        int c0 = k2 * 32 + (l >> 4) * 8;
        const float* rp = resp + n * 1024 + u * 64 + c0;
        float4 ra = *(const float4*)rp;
        float4 rb = *(const float4*)(rp + 4);
        int4 o;
        o.x = (int)packh2(ra.x, ra.y);
        o.y = (int)packh2(ra.z, ra.w);
        o.z = (int)packh2(rb.x, rb.y);
        o.w = (int)packh2(rb.z, rb.w);
        ((int4*)respF)[(n * 2 + k2) * 64 + l] = o;
    }
}

// ------------------------------------------------ PV for one tree (stride-52 gates)
__device__ inline void pv_tree(const char* gwb, const int4* rp4, int n, int t2,
                               int cl, int lq, int l, f32x4& o0, f32x4& o1) {
    const h16x2 onev = (h16x2){(h16)1.0f, (h16)1.0f};
    fragh rb0, rb1;
    rb0.i4 = rp4[(n * 2 + 0) * 64 + l];
    rb1.i4 = rp4[(n * 2 + 1) * 64 + l];
    #pragma unroll
    for (int rt = 0; rt < 2; ++rt) {
        int row = rt * 16 + cl;
        const u32a* gp = (const u32a*)(gwb + row * (GSTRIDE_U16 * 2) + t2 * 12);
        h2u g01u, g23u, g45u;
        g01u.u = gp[0]; g23u.u = gp[1]; g45u.u = gp[2];
        h16x2 g01 = g01u.h, g23 = g23u.h, g45 = g45u.h;
        h16x2 s01 = onev - g01;
        h16x2 s23 = onev - g23;
        h16x2 s45 = onev - g45;
        h16x2 gs0  = __builtin_shufflevector(g01, s01, 0, 2);
        h16x2 b1g  = __builtin_shufflevector(g01, g01, 1, 1);
        h16x2 b1s  = __builtin_shufflevector(s01, s01, 1, 1);
        h16x2 t01a = gs0 * b1g;
        h16x2 t01b = gs0 * b1s;
        h16x2 g2b  = __builtin_shufflevector(g23, g23, 0, 0);
        h16x2 s2b  = __builtin_shufflevector(s23, s23, 0, 0);
        h16x2 pa01 = t01a * g2b;
        h16x2 pa23 = t01b * g2b;
        h16x2 pa45 = t01a * s2b;
        h16x2 pa67 = t01b * s2b;
        h16 f3  = (lq & 1) ? s23[1] : g23[1];
        h16 f4  = (lq & 2) ? s45[0] : g45[0];
        h16 m34 = f3 * f4;
        h16 pbl = m34 * g45[1];    // bit5 = 0
        h16 pbh = m34 * s45[1];    // bit5 = 1
        h16x2 pblb = (h16x2){pbl, pbl};
        h16x2 pbhb = (h16x2){pbh, pbh};
        fragh fa1, fa2;
        fa1.h2[0] = pa01 * pblb; fa1.h2[1] = pa23 * pblb;
        fa1.h2[2] = pa45 * pblb; fa1.h2[3] = pa67 * pblb;
        fa2.h2[0] = pa01 * pbhb; fa2.h2[1] = pa23 * pbhb;
        fa2.h2[2] = pa45 * pbhb; fa2.h2[3] = pa67 * pbhb;
        if (rt == 0) {
            o0 = mfma_f16(fa1.v, rb0.v, o0);
            o0 = mfma_f16(fa2.v, rb1.v, o0);
        } else {
            o1 = mfma_f16(fa1.v, rb0.v, o1);
            o1 = mfma_f16(fa2.v, rb1.v, o1);
        }
    }
}

// ------------------------------------------------ main fused kernel
// grid 256 x 1024 threads (16 waves); BM=32.
// phase 0: stage x -> xf at [49152,65536)  [barrier]
// phase 1: kt-outer GEMM (16 xf reads/wave, 3 cts together)  [barrier]
// phase 2: EPI all 3 cts -> stride-52 gates slice (aliases xf tail, now dead)
//          -> PV 8 trees (conflict-free gate reads)
// finish : partials [barrier] cross-wave reduce -> out
__global__ __launch_bounds__(1024, 4) void k_main(const float* __restrict__ x,
                                                  const unsigned short* __restrict__ WpF,
                                                  const unsigned short* __restrict__ respF,
                                                  const float* __restrict__ bias,
                                                  float* __restrict__ out) {
    __shared__ char smemraw[65536];   // gates [0,53248) | xf [49152,65536)
    char* xfraw = smemraw + 49152;
    const int4* xf4 = (const int4*)xfraw;

    int tid = threadIdx.x;
    int w  = tid >> 6;      // wave 0..15
    int l  = tid & 63;
    int cl = l & 15;
    int lq = l >> 4;
    int rowbase = blockIdx.x * 32;
    int ctbase  = w * 3;    // 3 col-tiles (48 cols) per wave

    char* gwb = smemraw + w * GSLICE_B;   // wave's gates slice [32][52] u16
    const int4* wp4 = (const int4*)WpF;
    const int4* rp4 = (const int4*)respF;

    // -------- phase 0: stage x as fp16 A-frags (XOR-swizzled, at tail)
    {
        int k8  = tid & 31;
        int row = tid >> 5;
        const float* xp = x + (size_t)(rowbase + row) * 256 + k8 * 8;
        float4 xa = *(const float4*)(xp);
        float4 xb = *(const float4*)(xp + 4);
        int4 p;
        p.x = (int)packh2(xa.x, xa.y);
        p.y = (int)packh2(xa.z, xa.w);
        p.z = (int)packh2(xb.x, xb.y);
        p.w = (int)packh2(xb.z, xb.w);
        int rt = row >> 4, rl = row & 15, kt = k8 >> 2, klq = k8 & 3;
        char* basep = xfraw + (size_t)(rt * 8 + kt) * 1024
                            + (size_t)(((klq * 16 + rl) ^ kt) * 16);
        *(int4*)basep = p;
    }

    // issue kt=0 B-frags under the barrier wait
    fragh bc[3];
    #pragma unroll
    for (int j = 0; j < 3; ++j)
        bc[j].i4 = wp4[((ctbase + j) * 8 + 0) * 64 + l];
    MEMFENCE;

    __syncthreads();

    // -------- phase 1: kt-outer GEMM — 3 cts together, xf read once per kt
    f32x4 acc[3][2];
    #pragma unroll
    for (int j = 0; j < 3; ++j) {
        acc[j][0] = (f32x4){0.f, 0.f, 0.f, 0.f};
        acc[j][1] = (f32x4){0.f, 0.f, 0.f, 0.f};
    }

    #pragma unroll
    for (int kt = 0; kt < 8; ++kt) {
        fragh bn[3];
        if (kt < 7) {
            #pragma unroll
            for (int j = 0; j < 3; ++j)
                bn[j].i4 = wp4[((ctbase + j) * 8 + kt + 1) * 64 + l];
        }
        fragh a0, a1;
        a0.i4 = xf4[(0 * 8 + kt) * 64 + (l ^ kt)];
        a1.i4 = xf4[(1 * 8 + kt) * 64 + (l ^ kt)];
        #pragma unroll
        for (int j = 0; j < 3; ++j)
            acc[j][0] = mfma_f16(a0.v, bc[j].v, acc[j][0]);
        #pragma unroll
        for (int j = 0; j < 3; ++j)
            acc[j][1] = mfma_f16(a1.v, bc[j].v, acc[j][1]);
        if (kt < 7) { bc[0] = bn[0]; bc[1] = bn[1]; bc[2] = bn[2]; }
    }

    // prefetch respF for tree 0 (hides under EPI VALU)
    fragh rc0, rc1;
    rc0.i4 = rp4[((w * 8 + 0) * 2 + 0) * 64 + l];
    rc1.i4 = rp4[((w * 8 + 0) * 2 + 1) * 64 + l];
    MEMFENCE;

    __syncthreads();   // xf dead everywhere -> gates may alias its region

    // -------- phase 2a: EPI all 3 cts -> stride-52 gates (conflict-free)
    u16a* gw16 = (u16a*)gwb;
    #pragma unroll
    for (int j = 0; j < 3; ++j) {
        float bv = bias[(ctbase + j) * 16 + cl];
        #pragma unroll
        for (int rt = 0; rt < 2; ++rt) {
            #pragma unroll
            for (int r = 0; r < 4; ++r) {
                float g = acc[j][rt][r] + bv;
                g = fminf(fmaxf(g, 0.f), 1.f);
                gw16[(rt * 16 + lq * 4 + r) * GSTRIDE_U16 + j * 16 + cl] = h16r(g);
            }
        }
    }
    // wave-private slice: may_alias dependency + in-order DS completion.

    // -------- phase 2b: PV 8 trees (prefetched respF, depth-1)
    f32x4 oacc0 = (f32x4){0.f, 0.f, 0.f, 0.f};
    f32x4 oacc1 = (f32x4){0.f, 0.f, 0.f, 0.f};
    {
        // tree 0 uses rc0/rc1 via pv_tree's own loads? No: inline equivalent —
        // simply call pv_tree for each tree; L2-hot respF makes prefetch moot.
        pv_tree(gwb, rp4, w * 8 + 0, 0, cl, lq, l, oacc0, oacc1);
        pv_tree(gwb, rp4, w * 8 + 1, 1, cl, lq, l, oacc0, oacc1);
        pv_tree(gwb, rp4, w * 8 + 2, 2, cl, lq, l, oacc0, oacc1);
        pv_tree(gwb, rp4, w * 8 + 3, 3, cl, lq, l, oacc0, oacc1);
        pv_tree(gwb, rp4, w * 8 + 4, 4, cl, lq, l, oacc0, oacc1);
        pv_tree(gwb, rp4, w * 8 + 5, 5, cl, lq, l, oacc0, oacc1);
        pv_tree(gwb, rp4, w * 8 + 6, 6, cl, lq, l, oacc0, oacc1);
        pv_tree(gwb, rp4, w * 8 + 7, 7, cl, lq, l, oacc0, oacc1);
        (void)rc0; (void)rc1;
    }

    // -------- partials into own slice (gates dead), u-skewed
    {
        f32a* pw = (f32a*)gwb;
        int us = (cl + w) & 15;
        #pragma unroll
        for (int r = 0; r < 4; ++r) {
            pw[(lq * 4 + r) * 16 + us]        = oacc0[r];   // rows 0..15
            pw[(16 + lq * 4 + r) * 16 + us]   = oacc1[r];   // rows 16..31
        }
    }
    __syncthreads();

    // -------- cross-wave reduce: 16 waves' partials -> out
    if (tid < 512) {
        int r = tid >> 4, u = tid & 15;     // 32 rows x 16 u
        const f32a* pb = (const f32a*)smemraw;
        float s = 0.f;
        #pragma unroll
        for (int ww = 0; ww < 16; ++ww)
            s += pb[ww * (GSLICE_B / 4) + r * 16 + ((u + ww) & 15)];
        out[(size_t)(rowbase + r) * 16 + u] = s * (1.0f / 128.0f);
    }
}

// ------------------------------------------------ launch
extern "C" void kernel_launch(void* const* d_in, const int* in_sizes, int n_in,
                              void* d_out, int out_size, void* d_ws, size_t ws_size,
                              hipStream_t stream) {
    (void)in_sizes; (void)n_in; (void)out_size; (void)ws_size;
    const float* x    = (const float*)d_in[0];
    const float* fsl  = (const float*)d_in[1];
    const float* thr  = (const float*)d_in[2];
    const float* logt = (const float*)d_in[3];
    const float* resp = (const float*)d_in[4];

    char* ws = (char*)d_ws;
    unsigned short* WpF   = (unsigned short*)(ws + WPF_OFF);
    unsigned short* respF = (unsigned short*)(ws + RESPF_OFF);
    float*          bias  = (float*)(ws + BIAS_OFF);
    float* out = (float*)d_out;

    k_prep<<<48, 1024, 0, stream>>>(fsl, thr, logt, resp, WpF, respF, bias);
    k_main<<<256, 1024, 0, stream>>>(x, WpF, respF, bias, out);
}

// Round 17
// 19.998 us; speedup vs baseline: 1.0613x; 1.0613x over previous
//
#include <hip/hip_runtime.h>

// B=8192, F=256(K), N=128 trees, D=6, U=16, C=64
// cols = n*6+d  (768 total)
//
// FINAL (round 17) = round 13 exact restore — best measured: 20.10 us.
// Structure: k_prep (sparsemax->fp16 B-frags + resp->B-frags) + k_main
// (x->LDS A-frags, per-col-tile interleaved GEMM/epilogue/PV with
// wave-private gates, fp16 MFMA throughout, LDS cross-wave reduce).
// Session decomposition: ~9.3us graph/launch overhead + ~1.3us prep +
// ~9.5us k_main (latency-coupled; 7 structural variants within 9.3-10.5).

typedef float f32x4 __attribute__((ext_vector_type(4)));
typedef unsigned int u32;
typedef _Float16 h16;
typedef _Float16 h16x2 __attribute__((ext_vector_type(2)));
typedef _Float16 h16x8 __attribute__((ext_vector_type(8)));

typedef unsigned short __attribute__((may_alias)) u16a;
typedef u32            __attribute__((may_alias)) u32a;
typedef float          __attribute__((may_alias)) f32a;

#define MEMFENCE asm volatile("" ::: "memory")

// ws layout (bytes):
//   WpF   fp16 [48ct][8kt][64lane][8]  @ 0        393216 B
//   respF fp16 [128n][2kt][64lane][8]  @ 393216   262144 B
//   bias  f32  [768]                   @ 655360     3072 B
#define WPF_OFF   0
#define RESPF_OFF 393216
#define BIAS_OFF  655360

union h2u { h16x2 h; u32 u; };
union hbits { h16 h; unsigned short s; };
union fragh { u32 w[4]; h16x8 v; int4 i4; h16x2 h2[4]; };

__device__ inline unsigned short h16r(float f) {
    hbits t; t.h = (h16)f; return t.s;
}
__device__ inline u32 packh2(float a, float b) {
    h2u t; t.h[0] = (h16)a; t.h[1] = (h16)b; return t.u;
}

__device__ inline f32x4 mfma_f16(h16x8 a, h16x8 b, f32x4 c) {
    return __builtin_amdgcn_mfma_f32_16x16x32_f16(a, b, c, 0, 0, 0);
}

// ------------------------------------------------ merged prep kernel
__global__ __launch_bounds__(256) void k_prep(const float* __restrict__ fsl,
                                              const float* __restrict__ thr,
                                              const float* __restrict__ logt,
                                              const float* __restrict__ resp,
                                              unsigned short* __restrict__ WpF,
                                              unsigned short* __restrict__ respF,
                                              float* __restrict__ bias) {
    int bb  = blockIdx.x;
    int tid = threadIdx.x;
    if (bb < 128) {
        __shared__ unsigned short sm[8][192];
        int ib = (bb & 31) * 8;    // feature base (32 iblocks)
        int nb = (bb >> 5) * 32;   // tree base    (4 nblocks)
        int il = tid >> 5;         // 0..7 local feature
        int nl = tid & 31;         // 0..31 local tree
        int i = ib + il;
        int n = nb + nl;
        const float* zp = fsl + (i * 128 + n) * 6;

        float z[6], zs[6];
        #pragma unroll
        for (int d = 0; d < 6; ++d) { z[d] = zp[d]; zs[d] = z[d]; }
        #pragma unroll
        for (int a = 0; a < 5; ++a) {
            #pragma unroll
            for (int b = a + 1; b < 6; ++b) {
                float hi = fmaxf(zs[a], zs[b]);
                float lo = fminf(zs[a], zs[b]);
                zs[a] = hi; zs[b] = lo;
            }
        }
        float cs = 0.f, csel = 0.f;
        int   km = 1;
        #pragma unroll
        for (int k = 0; k < 6; ++k) {
            cs += zs[k];
            if (1.0f + (float)(k + 1) * zs[k] > cs) { km = k + 1; csel = cs; }
        }
        float tau = (csel - 1.0f) / (float)km;

        #pragma unroll
        for (int d = 0; d < 6; ++d) {
            float invT = expf(-logt[n * 6 + d]);
            float sel  = fmaxf(z[d] - tau, 0.0f);
            float wv   = sel * 0.5f * invT;
            sm[il][nl * 6 + d] = h16r(wv);
            if (i == 0) bias[n * 6 + d] = 0.5f - 0.5f * invT * thr[n * 6 + d];
        }
        __syncthreads();

        if (tid < 192) {
            int ct  = (nb * 6) / 16 + (tid >> 4);   // nb*6 is a multiple of 192
            int clm = tid & 15;
            int kt  = ib >> 5;
            int lq  = (ib >> 3) & 3;
            union { unsigned short s[8]; int4 i4; } o;
            #pragma unroll
            for (int j = 0; j < 8; ++j) o.s[j] = sm[j][tid];
            *(int4*)(WpF + (size_t)(((ct * 8 + kt) * 64 + lq * 16 + clm) * 8)) = o.i4;
        }
    } else {
        int t = (bb - 128) * 256 + tid;   // 16384 = 128 n * 2 kt * 64 lanes
        int n  = t >> 7;
        int k2 = (t >> 6) & 1;
        int l  = t & 63;
        int u  = l & 15;
        int c0 = k2 * 32 + (l >> 4) * 8;
        const float* rp = resp + n * 1024 + u * 64 + c0;   // resp[n][u][c]
        float4 ra = *(const float4*)rp;
        float4 rb = *(const float4*)(rp + 4);
        int4 o;
        o.x = (int)packh2(ra.x, ra.y);
        o.y = (int)packh2(ra.z, ra.w);
        o.z = (int)packh2(rb.x, rb.y);
        o.w = (int)packh2(rb.z, rb.w);
        ((int4*)respF)[(n * 2 + k2) * 64 + l] = o;
    }
}

// ------------------------------------------------ PV for one tree (wave-private gates)
__device__ inline void pv_tree(const u16a* gw, const int4* rp4, int n, int t2,
                               int cl, int lq, f32x4& o0, f32x4& o1) {
    const h16x2 onev = (h16x2){(h16)1.0f, (h16)1.0f};
    fragh rb0, rb1;
    rb0.i4 = rp4[(n * 2 + 0) * 64 + (lq * 16 + cl)];
    rb1.i4 = rp4[(n * 2 + 1) * 64 + (lq * 16 + cl)];
    #pragma unroll
    for (int rt = 0; rt < 2; ++rt) {
        int row = rt * 16 + cl;
        const u32a* gp = (const u32a*)((const char*)gw + row * 96 + t2 * 12);
        h2u g01u, g23u, g45u;
        g01u.u = gp[0]; g23u.u = gp[1]; g45u.u = gp[2];
        h16x2 g01 = g01u.h, g23 = g23u.h, g45 = g45u.h;
        h16x2 s01 = onev - g01;
        h16x2 s23 = onev - g23;
        h16x2 s45 = onev - g45;
        h16x2 gs0  = __builtin_shufflevector(g01, s01, 0, 2);
        h16x2 b1g  = __builtin_shufflevector(g01, g01, 1, 1);
        h16x2 b1s  = __builtin_shufflevector(s01, s01, 1, 1);
        h16x2 t01a = gs0 * b1g;
        h16x2 t01b = gs0 * b1s;
        h16x2 g2b  = __builtin_shufflevector(g23, g23, 0, 0);
        h16x2 s2b  = __builtin_shufflevector(s23, s23, 0, 0);
        h16x2 pa01 = t01a * g2b;
        h16x2 pa23 = t01b * g2b;
        h16x2 pa45 = t01a * s2b;
        h16x2 pa67 = t01b * s2b;
        h16 f3  = (lq & 1) ? s23[1] : g23[1];
        h16 f4  = (lq & 2) ? s45[0] : g45[0];
        h16 m34 = f3 * f4;
        h16 pbl = m34 * g45[1];
        h16 pbh = m34 * s45[1];
        h16x2 pblb = (h16x2){pbl, pbl};
        h16x2 pbhb = (h16x2){pbh, pbh};
        fragh fa1, fa2;
        fa1.h2[0] = pa01 * pblb; fa1.h2[1] = pa23 * pblb;
        fa1.h2[2] = pa45 * pblb; fa1.h2[3] = pa67 * pblb;
        fa2.h2[0] = pa01 * pbhb; fa2.h2[1] = pa23 * pbhb;
        fa2.h2[2] = pa45 * pbhb; fa2.h2[3] = pa67 * pbhb;
        if (rt == 0) {
            o0 = mfma_f16(fa1.v, rb0.v, o0);
            o0 = mfma_f16(fa2.v, rb1.v, o0);
        } else {
            o1 = mfma_f16(fa1.v, rb0.v, o1);
            o1 = mfma_f16(fa2.v, rb1.v, o1);
        }
    }
}

// ------------------------------------------------ main fused kernel (interleaved)
__global__ __launch_bounds__(1024, 4) void k_main(const float* __restrict__ x,
                                                  const unsigned short* __restrict__ WpF,
                                                  const unsigned short* __restrict__ respF,
                                                  const float* __restrict__ bias,
                                                  float* __restrict__ out) {
    __shared__ char smemraw[65536];          // xf [0,16K) | gates/partials 16K+w*3K
    const int4* xf4 = (const int4*)smemraw;

    int tid = threadIdx.x;
    int w  = tid >> 6;      // wave 0..15
    int l  = tid & 63;
    int cl = l & 15;
    int lq = l >> 4;
    int rowbase = blockIdx.x * 32;
    int ctbase  = w * 3;    // 3 col-tiles (48 cols) per wave

    u16a* gw = (u16a*)(smemraw + 16384 + w * 3072);  // [32][48] gates (own slice)
    const int4* wp4 = (const int4*)WpF;
    const int4* rp4 = (const int4*)respF;

    // -------- phase 0: stage x as fp16 A-frags
    {
        int k8  = tid & 31;
        int row = tid >> 5;
        const float* xp = x + (size_t)(rowbase + row) * 256 + k8 * 8;
        float4 xa = *(const float4*)(xp);
        float4 xb = *(const float4*)(xp + 4);
        int4 p;
        p.x = (int)packh2(xa.x, xa.y);
        p.y = (int)packh2(xa.z, xa.w);
        p.z = (int)packh2(xb.x, xb.y);
        p.w = (int)packh2(xb.z, xb.w);
        int rt = row >> 4, rl = row & 15, kt = k8 >> 2, klq = k8 & 3;
        char* basep = smemraw + (size_t)(rt * 8 + kt) * 1024
                              + (size_t)(((klq * 16 + rl) ^ kt) * 16);
        *(int4*)basep = p;
    }

    // issue ct0's B-frags — fly under the barrier wait
    fragh Bc[8], Bn[8];
    #pragma unroll
    for (int kt = 0; kt < 8; ++kt)
        Bc[kt].i4 = wp4[((ctbase + 0) * 8 + kt) * 64 + l];
    MEMFENCE;

    __syncthreads();

    f32x4 oacc0 = (f32x4){0.f, 0.f, 0.f, 0.f};
    f32x4 oacc1 = (f32x4){0.f, 0.f, 0.f, 0.f};
    f32x4 acc0, acc1;

#define GEMM_CT(CT, PREF)                                                   \
    acc0 = (f32x4){0.f, 0.f, 0.f, 0.f};                                     \
    acc1 = (f32x4){0.f, 0.f, 0.f, 0.f};                                     \
    _Pragma("unroll")                                                       \
    for (int kt = 0; kt < 8; ++kt) {                                        \
        if (PREF) Bn[kt].i4 = wp4[((ctbase + (CT) + 1) * 8 + kt) * 64 + l]; \
        fragh a0, a1;                                                       \
        a0.i4 = xf4[(0 * 8 + kt) * 64 + (l ^ kt)];                          \
        a1.i4 = xf4[(1 * 8 + kt) * 64 + (l ^ kt)];                          \
        acc0 = mfma_f16(a0.v, Bc[kt].v, acc0);                              \
        acc1 = mfma_f16(a1.v, Bc[kt].v, acc1);                              \
        MEMFENCE;                                                           \
    }

#define EPI_CT(CT) {                                                        \
    int colg = (ctbase + (CT)) * 16 + cl;                                   \
    float bv = bias[colg];                                                  \
    _Pragma("unroll")                                                       \
    for (int rt = 0; rt < 2; ++rt) {                                        \
        f32x4 av = rt ? acc1 : acc0;                                        \
        _Pragma("unroll")                                                   \
        for (int r = 0; r < 4; ++r) {                                       \
            float g = av[r] + bv;                                           \
            g = fminf(fmaxf(g, 0.f), 1.f);                                  \
            gw[(rt * 16 + lq * 4 + r) * 48 + (CT) * 16 + cl] = h16r(g);     \
        }                                                                   \
    } }

#define SWAPB _Pragma("unroll") for (int kk = 0; kk < 8; ++kk) Bc[kk] = Bn[kk];

    // ---- ct0: GEMM (issue ct1 B) -> gates cols 0..15 -> PV trees 0,1
    GEMM_CT(0, 1)
    EPI_CT(0)
    pv_tree(gw, rp4, w * 8 + 0, 0, cl, lq, oacc0, oacc1);
    pv_tree(gw, rp4, w * 8 + 1, 1, cl, lq, oacc0, oacc1);
    SWAPB

    // ---- ct1: GEMM (issue ct2 B) -> gates cols 16..31 -> PV trees 2,3,4
    GEMM_CT(1, 1)
    EPI_CT(1)
    pv_tree(gw, rp4, w * 8 + 2, 2, cl, lq, oacc0, oacc1);
    pv_tree(gw, rp4, w * 8 + 3, 3, cl, lq, oacc0, oacc1);
    pv_tree(gw, rp4, w * 8 + 4, 4, cl, lq, oacc0, oacc1);
    SWAPB

    // ---- ct2: GEMM -> gates cols 32..47 -> PV trees 5,6,7
    GEMM_CT(2, 0)
    EPI_CT(2)
    pv_tree(gw, rp4, w * 8 + 5, 5, cl, lq, oacc0, oacc1);
    pv_tree(gw, rp4, w * 8 + 6, 6, cl, lq, oacc0, oacc1);
    pv_tree(gw, rp4, w * 8 + 7, 7, cl, lq, oacc0, oacc1);

    // -------- partials into own slice (gates dead), u-skewed
    {
        f32a* pw = (f32a*)(smemraw + 16384 + w * 3072);
        int us = (cl + w) & 15;
        #pragma unroll
        for (int r = 0; r < 4; ++r) {
            pw[(lq * 4 + r) * 16 + us]        = oacc0[r];   // rows 0..15  (rt=0)
            pw[(16 + lq * 4 + r) * 16 + us]   = oacc1[r];   // rows 16..31 (rt=1)
        }
    }
    __syncthreads();

    // -------- cross-wave reduce: 16 waves' partials -> out
    if (tid < 512) {
        int r = tid >> 4, u = tid & 15;     // 32 rows x 16 u
        const f32a* pb = (const f32a*)(smemraw + 16384);
        float s = 0.f;
        #pragma unroll
        for (int ww = 0; ww < 16; ++ww)
            s += pb[ww * 768 + r * 16 + ((u + ww) & 15)];
        out[(size_t)(rowbase + r) * 16 + u] = s * (1.0f / 128.0f);
    }
}

// ------------------------------------------------ launch
extern "C" void kernel_launch(void* const* d_in, const int* in_sizes, int n_in,
                              void* d_out, int out_size, void* d_ws, size_t ws_size,
                              hipStream_t stream) {
    (void)in_sizes; (void)n_in; (void)out_size; (void)ws_size;
    const float* x    = (const float*)d_in[0];
    const float* fsl  = (const float*)d_in[1];
    const float* thr  = (const float*)d_in[2];
    const float* logt = (const float*)d_in[3];
    const float* resp = (const float*)d_in[4];

    char* ws = (char*)d_ws;
    unsigned short* WpF   = (unsigned short*)(ws + WPF_OFF);
    unsigned short* respF = (unsigned short*)(ws + RESPF_OFF);
    float*          bias  = (float*)(ws + BIAS_OFF);
    float* out = (float*)d_out;

    k_prep<<<192, 256, 0, stream>>>(fsl, thr, logt, resp, WpF, respF, bias);
    k_main<<<256, 1024, 0, stream>>>(x, WpF, respF, bias, out);
}